// Round 9
// baseline (220.564 us; speedup 1.0000x reference)
//
#include <hip/hip_runtime.h>

typedef __bf16 bf16x8 __attribute__((ext_vector_type(8)));
typedef float f32x4 __attribute__((ext_vector_type(4)));

#define AS1 __attribute__((address_space(1)))
#define AS3 __attribute__((address_space(3)))

__device__ __forceinline__ void gload_lds16(const void* g, void* l) {
  __builtin_amdgcn_global_load_lds((const AS1 void*)g, (AS3 void*)l, 16, 0, 0);
}

#define MFMA16(a, b, c) __builtin_amdgcn_mfma_f32_16x16x32_bf16((a), (b), (c), 0, 0, 0)
#define BARM asm volatile("s_barrier" ::: "memory")

// ---------------------------------------------------------------- fp32 -> bf16 (all 4 tensors, one dispatch)
__global__ __launch_bounds__(256)
void cvt_all(const float* __restrict__ sem, const float* __restrict__ wq,
             const float* __restrict__ wk, const float* __restrict__ wa,
             __bf16* __restrict__ semb, __bf16* __restrict__ wcat) {
  int i = blockIdx.x * 256 + threadIdx.x;
  if (i >= 2409472) return;
  const float* in;
  __bf16* out;
  int j;
  if (i < 1310720) { in = sem; out = semb; j = i; }
  else if (i < 1835008) { in = wq; out = wcat; j = i - 1310720; }
  else if (i < 2359296) { in = wk; out = wcat + 4194304; j = i - 1835008; }
  else { in = wa; out = wcat + 8388608; j = i - 2359296; }
  const float4* p = (const float4*)in;
  float4 a = p[2 * j], b = p[2 * j + 1];
  bf16x8 v;
  v[0] = (__bf16)a.x; v[1] = (__bf16)a.y; v[2] = (__bf16)a.z; v[3] = (__bf16)a.w;
  v[4] = (__bf16)b.x; v[5] = (__bf16)b.y; v[6] = (__bf16)b.z; v[7] = (__bf16)b.w;
  *(bf16x8*)(out + (size_t)j * 8) = v;
}

// ---------------------------------------------------------------- fused projection GEMM, 256x384, one-round grid
// C[5120,4608(pad)] = semb[5120,2048] @ Wcat[4292,2048]^T (B rows clamped).
// cols [0,2048)->Qb; [2048,4096)->Kb; [4096,4292)->adj sigmoid; rest dropped.
// 512 thr = 8 waves (2M x 4N), wave tile 128x96 (acc[8][6]). BK=32, 64 iters.
// Ring-3 (3 x 40 KiB): iter j computes slot j%3, stages tile j+2 into slot (j+2)%3.
// 4 barrier-sandwiched phases/iter (q00,q10,q11,q01), frag reads issued ONE PHASE AHEAD
// (drain under previous MFMA window), vmcnt(5) only at ph3 (forces tile j+1, staged a
// full iter ago; leaves tile j+2's 5 loads in flight). Chunk swizzle c^=(row>>1)&3
// folded into per-lane global source (2-way banks = free).
__global__ __launch_bounds__(512, 1)
void gemm_fused(const __bf16* __restrict__ A, const __bf16* __restrict__ B,
                const float* __restrict__ qbias, const float* __restrict__ kbias,
                const float* __restrict__ abias, __bf16* __restrict__ Qo,
                __bf16* __restrict__ Ko, float* __restrict__ adj) {
  __shared__ char smem[122880];  // 3 x 40960 (A 16K + B 24K per slot)
  char* smc = smem;
  // XCD chunking: 240 = 8 x 30 exact; tm-fast within chunk
  const int bid = blockIdx.x;
  const int wgid = (bid & 7) * 30 + (bid >> 3);
  const int tm = wgid % 20, tn = wgid / 20;

  const int t = threadIdx.x;
  const int lane = t & 63;
  const int w = t >> 6, wm = w >> 2, wn = w & 3;

  // ---- staging constants: 5 ops/tile (A: 2, B: 3); op = 128 rows x 64B
  const int trow = t >> 2;                         // 0..127
  const int gchunk = (t & 3) ^ ((trow >> 1) & 3);  // pre-swizzled global chunk
  const __bf16* gA0 = A + (size_t)(tm * 256 + trow) * 2048 + gchunk * 8;
  const __bf16* gA1 = gA0 + (size_t)128 * 2048;
  int br0 = tn * 384 + trow;       br0 = br0 < 4292 ? br0 : 4291;
  int br1 = tn * 384 + 128 + trow; br1 = br1 < 4292 ? br1 : 4291;
  int br2 = tn * 384 + 256 + trow; br2 = br2 < 4292 ? br2 : 4291;
  const __bf16* gB0 = B + (size_t)br0 * 2048 + gchunk * 8;
  const __bf16* gB1 = B + (size_t)br1 * 2048 + gchunk * 8;
  const __bf16* gB2 = B + (size_t)br2 * 2048 + gchunk * 8;
  const int dA0 = t * 16, dA1 = 8192 + t * 16;
  const int dB0 = 16384 + t * 16, dB1 = 24576 + t * 16, dB2 = 32768 + t * 16;

  // ---- fragment-read constants (swizzled chunk)
  const int L = lane & 15;
  const int xch = (((lane >> 4) ^ ((L >> 1) & 3)) << 4);
  const int aBase = (wm * 128 + L) * 64 + xch;           // + m*1024 (+slot)
  const int bBase = 16384 + (wn * 96 + L) * 64 + xch;    // + n*1024 (+slot)

  f32x4 acc[8][6];
#pragma unroll
  for (int m = 0; m < 8; ++m)
#pragma unroll
    for (int n = 0; n < 6; ++n) acc[m][n] = (f32x4){0.f, 0.f, 0.f, 0.f};

  // prologue: stage tiles 0,1 -> slots 0,1; force tile 0; preload a0,b0 of tile 0
  gload_lds16(gA0, smc + dA0); gload_lds16(gA1, smc + dA1);
  gload_lds16(gB0, smc + dB0); gload_lds16(gB1, smc + dB1); gload_lds16(gB2, smc + dB2);
  gload_lds16(gA0 + 32, smc + 40960 + dA0); gload_lds16(gA1 + 32, smc + 40960 + dA1);
  gload_lds16(gB0 + 32, smc + 40960 + dB0); gload_lds16(gB1 + 32, smc + 40960 + dB1);
  gload_lds16(gB2 + 32, smc + 40960 + dB2);
  asm volatile("s_waitcnt vmcnt(5)" ::: "memory");
  BARM;
  bf16x8 a0[4], b0[3];
#pragma unroll
  for (int m = 0; m < 4; ++m) a0[m] = *(const bf16x8*)(smc + aBase + m * 1024);
#pragma unroll
  for (int n = 0; n < 3; ++n) b0[n] = *(const bf16x8*)(smc + bBase + n * 1024);

  int co = 0, si = 2;
  for (int j = 0; j < 64; ++j) {
    const char* cu = smc + co * 40960;
    char* sg = smc + si * 40960;
    const int kb = (j + 2) * 32;  // staged tile column (elements)
    // ---- ph1: issue a1 reads; stage A(j+2); MFMA q00 (a0 x b0)
    bf16x8 na1[4];
#pragma unroll
    for (int m = 0; m < 4; ++m) na1[m] = *(const bf16x8*)(cu + aBase + (m + 4) * 1024);
    if (j < 62) { gload_lds16(gA0 + kb, sg + dA0); gload_lds16(gA1 + kb, sg + dA1); }
    BARM;
    __builtin_amdgcn_s_setprio(1);
#pragma unroll
    for (int m = 0; m < 4; ++m)
#pragma unroll
      for (int n = 0; n < 3; ++n) acc[m][n] = MFMA16(a0[m], b0[n], acc[m][n]);
    __builtin_amdgcn_s_setprio(0);
    BARM;
    // ---- ph2: issue b1 reads; stage B01(j+2); MFMA q10 (a1 x b0)
    bf16x8 nb1[3];
#pragma unroll
    for (int n = 0; n < 3; ++n) nb1[n] = *(const bf16x8*)(cu + bBase + (n + 3) * 1024);
    if (j < 62) { gload_lds16(gB0 + kb, sg + dB0); gload_lds16(gB1 + kb, sg + dB1); }
    BARM;
    __builtin_amdgcn_s_setprio(1);
#pragma unroll
    for (int m = 0; m < 4; ++m)
#pragma unroll
      for (int n = 0; n < 3; ++n) acc[m + 4][n] = MFMA16(na1[m], b0[n], acc[m + 4][n]);
    __builtin_amdgcn_s_setprio(0);
    BARM;
    // ---- ph3: stage B2(j+2); MFMA q11 (a1 x b1); counted vmcnt; barrier
    if (j < 62) gload_lds16(gB2 + kb, sg + dB2);
    BARM;
    __builtin_amdgcn_s_setprio(1);
#pragma unroll
    for (int m = 0; m < 4; ++m)
#pragma unroll
      for (int n = 0; n < 3; ++n) acc[m + 4][n + 3] = MFMA16(na1[m], nb1[n], acc[m + 4][n + 3]);
    __builtin_amdgcn_s_setprio(0);
    if (j < 62) asm volatile("s_waitcnt vmcnt(5)" ::: "memory");
    else if (j == 62) asm volatile("s_waitcnt vmcnt(0)" ::: "memory");
    BARM;
    // ---- ph4: issue next-tile a0,b0 reads (slot (j+1)%3, safe after vmcnt+bar); MFMA q01 (a0 x b1)
    bf16x8 a0n[4];
    const int cn = (co == 2) ? 0 : co + 1;
    const char* nx = smc + cn * 40960;
    if (j < 63) {
#pragma unroll
      for (int m = 0; m < 4; ++m) a0n[m] = *(const bf16x8*)(nx + aBase + m * 1024);
#pragma unroll
      for (int n = 0; n < 3; ++n) b0[n] = *(const bf16x8*)(nx + bBase + n * 1024);
    }
    __builtin_amdgcn_s_setprio(1);
#pragma unroll
    for (int m = 0; m < 4; ++m)
#pragma unroll
      for (int n = 0; n < 3; ++n) acc[m][n + 3] = MFMA16(a0[m], nb1[n], acc[m][n + 3]);
    __builtin_amdgcn_s_setprio(0);
    BARM;
#pragma unroll
    for (int m = 0; m < 4; ++m) a0[m] = a0n[m];
    co = cn;
    si = (si == 2) ? 0 : si + 1;
  }
  __syncthreads();

  // ---- epilogue 1: adj region (cols 4096..4291), direct f32 sigmoid stores
#pragma unroll
  for (int n = 0; n < 6; ++n) {
    const int col = tn * 384 + wn * 96 + n * 16 + L;
    if (col >= 4096 && col < 4292) {
      const float bv = abias[col - 4096];
#pragma unroll
      for (int m = 0; m < 8; ++m)
#pragma unroll
        for (int jj = 0; jj < 4; ++jj) {
          const int row = tm * 256 + wm * 128 + m * 16 + (lane >> 4) * 4 + jj;
          const float v = acc[m][n][jj] + bv;
          adj[(size_t)row * 196 + (col - 4096)] = 1.f / (1.f + __expf(-v));
        }
    }
  }
  // ---- epilogue 2: Q/K via LDS transpose, two half-row passes, coalesced 16B stores
  __bf16* so = (__bf16*)smc;  // [128][392]
#pragma unroll
  for (int rh = 0; rh < 2; ++rh) {
    if (wm == rh) {
#pragma unroll
      for (int n = 0; n < 6; ++n) {
        const int col = tn * 384 + wn * 96 + n * 16 + L;
        if (col < 4096) {
          const float bv = col < 2048 ? qbias[col] : kbias[col - 2048];
          const int lcol = wn * 96 + n * 16 + L;
#pragma unroll
          for (int m = 0; m < 8; ++m) {
            const int lr = m * 16 + (lane >> 4) * 4;
#pragma unroll
            for (int jj = 0; jj < 4; ++jj)
              so[(lr + jj) * 392 + lcol] = (__bf16)(acc[m][n][jj] + bv);
          }
        }
      }
    }
    __syncthreads();
    for (int idx = t; idx < 6144; idx += 512) {  // 128 rows x 48 chunks
      const int lr = idx / 48, ch = idx - lr * 48;
      const int gcol = tn * 384 + ch * 8;
      if (gcol < 4096) {
        const int grow = tm * 256 + rh * 128 + lr;
        __bf16* dst = (gcol < 2048) ? (Qo + (size_t)grow * 2048 + gcol)
                                    : (Ko + (size_t)grow * 2048 + (gcol - 2048));
        *(bf16x8*)dst = *(const bf16x8*)(so + lr * 392 + ch * 8);
      }
    }
    __syncthreads();
  }
}

// ---------------------------------------------------------------- attention 1/3: partial S
__global__ __launch_bounds__(256)
void attn_s(const __bf16* __restrict__ Qb, const __bf16* __restrict__ Kb,
            float* __restrict__ Spart) {
  __shared__ char smem[81920];
  __bf16* sQ = (__bf16*)smem;            // [80][256]
  __bf16* sK = (__bf16*)(smem + 40960);  // [80][256]
  const int b = blockIdx.x >> 3, kq = blockIdx.x & 7;
  const int kc = kq * 256;
  const int t = threadIdx.x, lane = t & 63, w = t >> 6;
  const __bf16* Qbase = Qb + (size_t)b * 163840;
  const __bf16* Kbase = Kb + (size_t)b * 163840;

#pragma unroll
  for (int s = 0; s < 10; ++s) {
    const int i = t + s * 256;
    const int row = i >> 5, cb = i & 31;
    gload_lds16(Qbase + (size_t)row * 2048 + kc + cb * 8, sQ + i * 8);
  }
#pragma unroll
  for (int s = 0; s < 10; ++s) {
    const int i = t + s * 256;
    const int row = i >> 5, cb = i & 31;
    gload_lds16(Kbase + (size_t)row * 2048 + kc + cb * 8, sK + i * 8);
  }
  __syncthreads();

  f32x4 acc[7];
#pragma unroll
  for (int u = 0; u < 7; ++u) acc[u] = (f32x4){0.f, 0.f, 0.f, 0.f};
#pragma unroll
  for (int u = 0; u < 7; ++u) {
    const int tl = w + u * 4;
    if (tl < 25) {
      const int qi = tl / 5, kj = tl % 5;
#pragma unroll
      for (int k0 = 0; k0 < 256; k0 += 32) {
        bf16x8 a = *(const bf16x8*)(sQ + (qi * 16 + (lane & 15)) * 256 + k0 + (lane >> 4) * 8);
        bf16x8 kk = *(const bf16x8*)(sK + (kj * 16 + (lane & 15)) * 256 + k0 + (lane >> 4) * 8);
        acc[u] = MFMA16(a, kk, acc[u]);
      }
    }
  }
  float* Sp = Spart + (size_t)(b * 8 + kq) * 6400;
#pragma unroll
  for (int u = 0; u < 7; ++u) {
    const int tl = w + u * 4;
    if (tl < 25) {
      const int qi = tl / 5, kj = tl % 5;
#pragma unroll
      for (int jj = 0; jj < 4; ++jj) {
        const int r = qi * 16 + (lane >> 4) * 4 + jj;
        const int c = kj * 16 + (lane & 15);
        Sp[r * 80 + c] = acc[u][jj];
      }
    }
  }
}

// ---------------------------------------------------------------- attention 2/3: softmax
__global__ __launch_bounds__(256)
void attn_soft(const float* __restrict__ Spart, const float* __restrict__ mask,
               __bf16* __restrict__ Pg) {
  __shared__ float S[80 * 81];
  const int b = blockIdx.x, t = threadIdx.x;
  const float* Sp = Spart + (size_t)b * 8 * 6400;
  for (int idx = t; idx < 6400; idx += 256) {
    float s = 0.f;
#pragma unroll
    for (int p = 0; p < 8; ++p) s += Sp[p * 6400 + idx];
    const int r = idx / 80, c = idx - r * 80;
    S[r * 81 + c] = s;
  }
  __syncthreads();
  if (t < 80) {
    const float scale = 0.02209708691207961f;  // 1/sqrt(2048)
    float mx = -1e30f;
    for (int k = 0; k < 80; ++k) {
      float v = S[t * 81 + k] * scale * mask[t * 80 + k];
      S[t * 81 + k] = v;
      mx = fmaxf(mx, v);
    }
    float sum = 0.f;
    for (int k = 0; k < 80; ++k) {
      float e = __expf(S[t * 81 + k] - mx);
      S[t * 81 + k] = e;
      sum += e;
    }
    const float r = 1.f / sum;
    __bf16* Pr = Pg + (size_t)b * 7680 + t * 96;
    for (int k = 0; k < 80; ++k) Pr[k] = (__bf16)(S[t * 81 + k] * r);
    for (int k = 80; k < 96; ++k) Pr[k] = (__bf16)0.f;
  }
}

// ---------------------------------------------------------------- attention 3/3: PV + epilogue
__global__ __launch_bounds__(256)
void attn_pv(const __bf16* __restrict__ Pg, const float* __restrict__ feats,
             const float* __restrict__ adj, float* __restrict__ out) {
  __shared__ __bf16 Ft[64 * 104];
  const int b = blockIdx.x >> 2, hq = blockIdx.x & 3;
  const int hb = hq * 49;
  const int t = threadIdx.x, lane = t & 63, w = t >> 6;
  for (int idx = t; idx < 4704; idx += 256) {  // 96*49
    const int k = idx / 49, h = idx - k * 49;
    Ft[h * 104 + k] = (k < 80) ? (__bf16)feats[(size_t)b * 15680 + k * 196 + hb + h]
                               : (__bf16)0.f;
  }
  __syncthreads();
  const __bf16* Pb = Pg + (size_t)b * 7680;
#pragma unroll
  for (int u = 0; u < 5; ++u) {
    const int tl = w + u * 4;  // 0..19
    const int ci = tl >> 2, hj = tl & 3;
    f32x4 a2 = (f32x4){0.f, 0.f, 0.f, 0.f};
#pragma unroll
    for (int k0 = 0; k0 < 96; k0 += 32) {
      bf16x8 pa = *(const bf16x8*)(Pb + (ci * 16 + (lane & 15)) * 96 + k0 + (lane >> 4) * 8);
      bf16x8 fb = *(const bf16x8*)(Ft + (hj * 16 + (lane & 15)) * 104 + k0 + (lane >> 4) * 8);
      a2 = MFMA16(pa, fb, a2);
    }
#pragma unroll
    for (int jj = 0; jj < 4; ++jj) {
      const int c = ci * 16 + (lane >> 4) * 4 + jj;
      const int h2 = hj * 16 + (lane & 15);
      if (h2 < 49) {
        const size_t o = (size_t)b * 15680 + (size_t)c * 196 + hb + h2;
        out[o] = (feats[o] + a2[jj]) * adj[o];
      }
    }
  }
}

// ---------------------------------------------------------------- launch
extern "C" void kernel_launch(void* const* d_in, const int* in_sizes, int n_in,
                              void* d_out, int out_size, void* d_ws, size_t ws_size,
                              hipStream_t stream) {
  const float* features = (const float*)d_in[0];
  const float* sem      = (const float*)d_in[1];
  const float* mask     = (const float*)d_in[2];
  const float* Wq_w     = (const float*)d_in[3];
  const float* Wq_b     = (const float*)d_in[4];
  const float* Wk_w     = (const float*)d_in[5];
  const float* Wk_b     = (const float*)d_in[6];
  const float* Wa_w     = (const float*)d_in[7];
  const float* Wa_b     = (const float*)d_in[8];
  float* out = (float*)d_out;

  char* ws = (char*)d_ws;
  __bf16* semb = (__bf16*)ws;                   // 5120x2048 bf16
  __bf16* wcat = (__bf16*)(ws + 20971520);      // 4292x2048 bf16
  __bf16* Qb   = (__bf16*)(ws + 38551552);
  __bf16* Kb   = (__bf16*)(ws + 59523072);
  float*  adj  = (float*)(ws + 80494592);       // 5120x196 f32 (total 84.5 MB)
  float*  Spart = (float*)ws;                   // 64*8*6400 f32 = 13.1 MB (aliases semb)
  __bf16* Pg    = (__bf16*)(ws + 20971520);     // aliases wcat (dead after gemm)

  cvt_all<<<9412, 256, 0, stream>>>(sem, Wq_w, Wk_w, Wa_w, semb, wcat);
  gemm_fused<<<240, 512, 0, stream>>>(semb, wcat, Wq_b, Wk_b, Wa_b, Qb, Kb, adj);
  attn_s<<<512, 256, 0, stream>>>(Qb, Kb, Spart);
  attn_soft<<<64, 256, 0, stream>>>(Spart, mask, Pg);
  attn_pv<<<256, 256, 0, stream>>>(Pg, features, adj, out);
}

// Round 10
// 168.237 us; speedup vs baseline: 1.3110x; 1.3110x over previous
//
#include <hip/hip_runtime.h>

typedef __bf16 bf16x8 __attribute__((ext_vector_type(8)));
typedef float f32x4 __attribute__((ext_vector_type(4)));

#define AS1 __attribute__((address_space(1)))
#define AS3 __attribute__((address_space(3)))

__device__ __forceinline__ void gload_lds16(const void* g, void* l) {
  __builtin_amdgcn_global_load_lds((const AS1 void*)g, (AS3 void*)l, 16, 0, 0);
}

#define MFMA16(a, b, c) __builtin_amdgcn_mfma_f32_16x16x32_bf16((a), (b), (c), 0, 0, 0)

// ---------------------------------------------------------------- fp32 -> bf16 (all 4 tensors, one dispatch)
__global__ __launch_bounds__(256)
void cvt_all(const float* __restrict__ sem, const float* __restrict__ wq,
             const float* __restrict__ wk, const float* __restrict__ wa,
             __bf16* __restrict__ semb, __bf16* __restrict__ wcat) {
  int i = blockIdx.x * 256 + threadIdx.x;
  if (i >= 2409472) return;
  const float* in;
  __bf16* out;
  int j;
  if (i < 1310720) { in = sem; out = semb; j = i; }
  else if (i < 1835008) { in = wq; out = wcat; j = i - 1310720; }
  else if (i < 2359296) { in = wk; out = wcat + 4194304; j = i - 1835008; }
  else { in = wa; out = wcat + 8388608; j = i - 2359296; }
  const float4* p = (const float4*)in;
  float4 a = p[2 * j], b = p[2 * j + 1];
  bf16x8 v;
  v[0] = (__bf16)a.x; v[1] = (__bf16)a.y; v[2] = (__bf16)a.z; v[3] = (__bf16)a.w;
  v[4] = (__bf16)b.x; v[5] = (__bf16)b.y; v[6] = (__bf16)b.z; v[7] = (__bf16)b.w;
  *(bf16x8*)(out + (size_t)j * 8) = v;
}

// ---------------------------------------------------------------- fused projection GEMM
// C[5184(pad),4352] = semb[5120,2048] @ Wcat[4292,2048]^T (rows clamped).
// cols [0,2048)->Qb bf16 +qb; [2048,4096)->Kb bf16 +kb; [4096,4292)->adj sigmoid.
// Synthesis of proven parts: r8 geometry (4 waves 2Mx2N, wave tile 96x64, acc[6][4])
// + r6 schedule (BK=64, XOR-x16 swizzled staging via global_load_lds, double-buffer,
// one vmcnt(0)+barrier per iter, setprio MFMA clusters). LDS = 2 x 40960 = 80 KiB
// exactly -> 2 blocks/CU (cross-block overlap hides staging latency, m97/m114).
// ds-read bytes vs MFMA cycles per block-iter: 80 KB (~960 cy) vs 192 MFMA (~931 cy).
__global__ __launch_bounds__(256, 2)
void gemm_fused(const __bf16* __restrict__ A, const __bf16* __restrict__ B,
                const float* __restrict__ qbias, const float* __restrict__ kbias,
                const float* __restrict__ abias, __bf16* __restrict__ Qo,
                __bf16* __restrict__ Ko, float* __restrict__ adj) {
  __shared__ char smem[81920];
  char* smc = smem;
  // bijective XCD chunking (nwg=918, q=114, r=6) + 8-wide tn-band, tm-major in band
  const int bid = blockIdx.x;
  const int xcd = bid & 7, sidx = bid >> 3;
  const int wgid = (xcd < 6 ? xcd * 115 : 690 + (xcd - 6) * 114) + sidx;
  int tm, tn;
  if (wgid < 864) {
    const int band = wgid / 216, rem = wgid % 216;
    tm = rem >> 3;
    tn = band * 8 + (rem & 7);
  } else {
    const int rem = wgid - 864;
    tm = rem >> 1;
    tn = 32 + (rem & 1);
  }

  const int t = threadIdx.x;
  const int lane = t & 63;
  const int w = t >> 6, wm = w >> 1, wn = w & 1;  // 4 waves: 2M x 2N, wave tile 96x64

  // staging constants (linear LDS dest; swizzle folded into global source column)
  const int r0 = t >> 3;                       // 0..31 (row within 32-row op)
  const int colx = ((t & 7) ^ (r0 & 7)) * 8;   // pre-swizzled source column (elements)
  const int t16 = t * 16;

  // A: 6 ops x 32 rows (192 rows x 128 B = 24576 B); B: 4 ops x 32 rows (16384 B)
#define STAGE(kk, pb) do {                                                         \
    char* dst = smc + (pb);                                                        \
    _Pragma("unroll")                                                              \
    for (int i = 0; i < 6; ++i) {                                                  \
      int gr = tm * 192 + i * 32 + r0; gr = gr < 5120 ? gr : 5119;                 \
      gload_lds16(A + (size_t)gr * 2048 + (kk) * 64 + colx, dst + i * 4096 + t16); \
    }                                                                              \
    _Pragma("unroll")                                                              \
    for (int i = 0; i < 4; ++i) {                                                  \
      int gr = tn * 128 + i * 32 + r0; gr = gr < 4292 ? gr : 4291;                 \
      gload_lds16(B + (size_t)gr * 2048 + (kk) * 64 + colx,                        \
                  dst + 24576 + i * 4096 + t16);                                   \
    }                                                                              \
  } while (0)

  // fragment-read constants (swizzled ds_read, r6-proven)
  const int rbase = (lane & 15) * 128;
  const int g16 = (lane >> 4) * 16;
  const int x16 = (lane & 7) << 4;
  const int aoff = wm * 12288 + rbase;           // wm*96 rows * 128B
  const int boff = 24576 + wn * 8192 + rbase;    // wn*64 rows * 128B

#define LDA(sb, m, kh) (*(const bf16x8*)(smc + (sb) + aoff + (m) * 2048 + ((((kh) * 64) + g16) ^ x16)))
#define LDB(sb, n, kh) (*(const bf16x8*)(smc + (sb) + boff + (n) * 2048 + ((((kh) * 64) + g16) ^ x16)))

  f32x4 acc[6][4];
#pragma unroll
  for (int m = 0; m < 6; ++m)
#pragma unroll
    for (int n = 0; n < 4; ++n) acc[m][n] = (f32x4){0.f, 0.f, 0.f, 0.f};

  // prologue: tile 0 -> buffer 0
  STAGE(0, 0);
  asm volatile("s_waitcnt vmcnt(0)" ::: "memory");
  __builtin_amdgcn_s_barrier();

  for (int j = 0; j < 32; ++j) {
    const int sb = (j & 1) * 40960;
    // cluster 1: kh=0 frags; issue next-tile staging
    bf16x8 af0[6], bf0[4];
#pragma unroll
    for (int m = 0; m < 6; ++m) af0[m] = LDA(sb, m, 0);
#pragma unroll
    for (int n = 0; n < 4; ++n) bf0[n] = LDB(sb, n, 0);
    if (j < 31) STAGE(j + 1, 40960 - sb);
    __builtin_amdgcn_s_setprio(1);
#pragma unroll
    for (int m = 0; m < 6; ++m)
#pragma unroll
      for (int n = 0; n < 4; ++n) acc[m][n] = MFMA16(af0[m], bf0[n], acc[m][n]);
    __builtin_amdgcn_s_setprio(0);
    // cluster 2: kh=1 frags
    bf16x8 af1[6], bf1[4];
#pragma unroll
    for (int m = 0; m < 6; ++m) af1[m] = LDA(sb, m, 1);
#pragma unroll
    for (int n = 0; n < 4; ++n) bf1[n] = LDB(sb, n, 1);
    __builtin_amdgcn_s_setprio(1);
#pragma unroll
    for (int m = 0; m < 6; ++m)
#pragma unroll
      for (int n = 0; n < 4; ++n) acc[m][n] = MFMA16(af1[m], bf1[n], acc[m][n]);
    __builtin_amdgcn_s_setprio(0);
    if (j < 31) asm volatile("s_waitcnt vmcnt(0)" ::: "memory");
    __builtin_amdgcn_s_barrier();
  }

  // ---- epilogue
  if (tn < 32) {
    // bias-add + bf16 into LDS [192][136], then coalesced 16B row-major stores
    __bf16* so = (__bf16*)smc;
    const float* bias = (tn < 16) ? (qbias + tn * 128) : (kbias + (tn - 16) * 128);
#pragma unroll
    for (int n = 0; n < 4; ++n) {
      const int colb = wn * 64 + n * 16 + (lane & 15);
      const float bv = bias[colb];
#pragma unroll
      for (int m = 0; m < 6; ++m) {
        const int rw = wm * 96 + m * 16 + (lane >> 4) * 4;
#pragma unroll
        for (int jj = 0; jj < 4; ++jj)
          so[(rw + jj) * 136 + colb] = (__bf16)(acc[m][n][jj] + bv);
      }
    }
    __syncthreads();
    __bf16* dst = (tn < 16) ? (Qo + tn * 128) : (Ko + (tn - 16) * 128);
    for (int idx = t; idx < 3072; idx += 256) {  // 192 rows x 16 16B-chunks
      const int row = idx >> 4, c = idx & 15;
      const int grow = tm * 192 + row;
      if (grow < 5120) {
        bf16x8 v = *(const bf16x8*)(so + row * 136 + c * 8);
        *(bf16x8*)(dst + (size_t)grow * 2048 + c * 8) = v;
      }
    }
  } else {
    // adj region (cols 4096..4291): scattered f32 sigmoid stores (small)
#pragma unroll
    for (int n = 0; n < 4; ++n) {
      const int colg = (tn - 32) * 128 + wn * 64 + n * 16 + (lane & 15);
      if (colg < 196) {
        const float bv = abias[colg];
#pragma unroll
        for (int m = 0; m < 6; ++m)
#pragma unroll
          for (int jj = 0; jj < 4; ++jj) {
            const int row = tm * 192 + wm * 96 + m * 16 + (lane >> 4) * 4 + jj;
            if (row < 5120) {
              const float v = acc[m][n][jj] + bv;
              adj[(size_t)row * 196 + colg] = 1.f / (1.f + __expf(-v));
            }
          }
      }
    }
  }
#undef STAGE
#undef LDA
#undef LDB
}

// ---------------------------------------------------------------- attention 1/3: partial S
// grid (64 b x 8 kq): S_part[b][kq] = Q_b[:, kq*256..+256] @ K_b[...]^T  (f32 80x80)
__global__ __launch_bounds__(256)
void attn_s(const __bf16* __restrict__ Qb, const __bf16* __restrict__ Kb,
            float* __restrict__ Spart) {
  __shared__ char smem[81920];
  __bf16* sQ = (__bf16*)smem;            // [80][256]
  __bf16* sK = (__bf16*)(smem + 40960);  // [80][256]
  const int b = blockIdx.x >> 3, kq = blockIdx.x & 7;
  const int kc = kq * 256;
  const int t = threadIdx.x, lane = t & 63, w = t >> 6;
  const __bf16* Qbase = Qb + (size_t)b * 163840;
  const __bf16* Kbase = Kb + (size_t)b * 163840;

#pragma unroll
  for (int s = 0; s < 10; ++s) {
    const int i = t + s * 256;
    const int row = i >> 5, cb = i & 31;
    gload_lds16(Qbase + (size_t)row * 2048 + kc + cb * 8, sQ + i * 8);
  }
#pragma unroll
  for (int s = 0; s < 10; ++s) {
    const int i = t + s * 256;
    const int row = i >> 5, cb = i & 31;
    gload_lds16(Kbase + (size_t)row * 2048 + kc + cb * 8, sK + i * 8);
  }
  __syncthreads();

  f32x4 acc[7];
#pragma unroll
  for (int u = 0; u < 7; ++u) acc[u] = (f32x4){0.f, 0.f, 0.f, 0.f};
#pragma unroll
  for (int u = 0; u < 7; ++u) {
    const int tl = w + u * 4;
    if (tl < 25) {
      const int qi = tl / 5, kj = tl % 5;
#pragma unroll
      for (int k0 = 0; k0 < 256; k0 += 32) {
        bf16x8 a = *(const bf16x8*)(sQ + (qi * 16 + (lane & 15)) * 256 + k0 + (lane >> 4) * 8);
        bf16x8 kk = *(const bf16x8*)(sK + (kj * 16 + (lane & 15)) * 256 + k0 + (lane >> 4) * 8);
        acc[u] = MFMA16(a, kk, acc[u]);
      }
    }
  }
  float* Sp = Spart + (size_t)(b * 8 + kq) * 6400;
#pragma unroll
  for (int u = 0; u < 7; ++u) {
    const int tl = w + u * 4;
    if (tl < 25) {
      const int qi = tl / 5, kj = tl % 5;
#pragma unroll
      for (int jj = 0; jj < 4; ++jj) {
        const int r = qi * 16 + (lane >> 4) * 4 + jj;
        const int c = kj * 16 + (lane & 15);
        Sp[r * 80 + c] = acc[u][jj];
      }
    }
  }
}

// ---------------------------------------------------------------- attention 2/3: softmax
__global__ __launch_bounds__(256)
void attn_soft(const float* __restrict__ Spart, const float* __restrict__ mask,
               __bf16* __restrict__ Pg) {
  __shared__ float S[80 * 81];
  const int b = blockIdx.x, t = threadIdx.x;
  const float* Sp = Spart + (size_t)b * 8 * 6400;
  for (int idx = t; idx < 6400; idx += 256) {
    float s = 0.f;
#pragma unroll
    for (int p = 0; p < 8; ++p) s += Sp[p * 6400 + idx];
    const int r = idx / 80, c = idx - r * 80;
    S[r * 81 + c] = s;
  }
  __syncthreads();
  if (t < 80) {
    const float scale = 0.02209708691207961f;  // 1/sqrt(2048)
    float mx = -1e30f;
    for (int k = 0; k < 80; ++k) {
      float v = S[t * 81 + k] * scale * mask[t * 80 + k];
      S[t * 81 + k] = v;
      mx = fmaxf(mx, v);
    }
    float sum = 0.f;
    for (int k = 0; k < 80; ++k) {
      float e = __expf(S[t * 81 + k] - mx);
      S[t * 81 + k] = e;
      sum += e;
    }
    const float r = 1.f / sum;
    __bf16* Pr = Pg + (size_t)b * 7680 + t * 96;
    for (int k = 0; k < 80; ++k) Pr[k] = (__bf16)(S[t * 81 + k] * r);
    for (int k = 80; k < 96; ++k) Pr[k] = (__bf16)0.f;
  }
}

// ---------------------------------------------------------------- attention 3/3: PV + epilogue
__global__ __launch_bounds__(256)
void attn_pv(const __bf16* __restrict__ Pg, const float* __restrict__ feats,
             const float* __restrict__ adj, float* __restrict__ out) {
  __shared__ __bf16 Ft[64 * 104];
  const int b = blockIdx.x >> 2, hq = blockIdx.x & 3;
  const int hb = hq * 49;
  const int t = threadIdx.x, lane = t & 63, w = t >> 6;
  for (int idx = t; idx < 4704; idx += 256) {  // 96*49
    const int k = idx / 49, h = idx - k * 49;
    Ft[h * 104 + k] = (k < 80) ? (__bf16)feats[(size_t)b * 15680 + k * 196 + hb + h]
                               : (__bf16)0.f;
  }
  __syncthreads();
  const __bf16* Pb = Pg + (size_t)b * 7680;
#pragma unroll
  for (int u = 0; u < 5; ++u) {
    const int tl = w + u * 4;  // 0..19
    const int ci = tl >> 2, hj = tl & 3;
    f32x4 a2 = (f32x4){0.f, 0.f, 0.f, 0.f};
#pragma unroll
    for (int k0 = 0; k0 < 96; k0 += 32) {
      bf16x8 pa = *(const bf16x8*)(Pb + (ci * 16 + (lane & 15)) * 96 + k0 + (lane >> 4) * 8);
      bf16x8 fb = *(const bf16x8*)(Ft + (hj * 16 + (lane & 15)) * 104 + k0 + (lane >> 4) * 8);
      a2 = MFMA16(pa, fb, a2);
    }
#pragma unroll
    for (int jj = 0; jj < 4; ++jj) {
      const int c = ci * 16 + (lane >> 4) * 4 + jj;
      const int h2 = hj * 16 + (lane & 15);
      if (h2 < 49) {
        const size_t o = (size_t)b * 15680 + (size_t)c * 196 + hb + h2;
        out[o] = (feats[o] + a2[jj]) * adj[o];
      }
    }
  }
}

// ---------------------------------------------------------------- launch
extern "C" void kernel_launch(void* const* d_in, const int* in_sizes, int n_in,
                              void* d_out, int out_size, void* d_ws, size_t ws_size,
                              hipStream_t stream) {
  const float* features = (const float*)d_in[0];
  const float* sem      = (const float*)d_in[1];
  const float* mask     = (const float*)d_in[2];
  const float* Wq_w     = (const float*)d_in[3];
  const float* Wq_b     = (const float*)d_in[4];
  const float* Wk_w     = (const float*)d_in[5];
  const float* Wk_b     = (const float*)d_in[6];
  const float* Wa_w     = (const float*)d_in[7];
  const float* Wa_b     = (const float*)d_in[8];
  float* out = (float*)d_out;

  char* ws = (char*)d_ws;
  __bf16* semb = (__bf16*)ws;                   // 5120x2048 bf16
  __bf16* wcat = (__bf16*)(ws + 20971520);      // 4292x2048 bf16
  __bf16* Qb   = (__bf16*)(ws + 38551552);
  __bf16* Kb   = (__bf16*)(ws + 59523072);
  float*  adj  = (float*)(ws + 80494592);       // 5120x196 f32 (total 84.5 MB)
  float*  Spart = (float*)ws;                   // 64*8*6400 f32 = 13.1 MB (aliases semb)
  __bf16* Pg    = (__bf16*)(ws + 20971520);     // aliases wcat (dead after gemm)

  cvt_all<<<9412, 256, 0, stream>>>(sem, Wq_w, Wk_w, Wa_w, semb, wcat);
  gemm_fused<<<918, 256, 0, stream>>>(semb, wcat, Wq_b, Wk_b, Wa_b, Qb, Kb, adj);
  attn_s<<<512, 256, 0, stream>>>(Qb, Kb, Spart);
  attn_soft<<<64, 256, 0, stream>>>(Spart, mask, Pg);
  attn_pv<<<256, 256, 0, stream>>>(Pg, features, adj, out);
}

// Round 11
// 158.652 us; speedup vs baseline: 1.3902x; 1.0604x over previous
//
#include <hip/hip_runtime.h>

typedef __bf16 bf16x8 __attribute__((ext_vector_type(8)));
typedef float f32x4 __attribute__((ext_vector_type(4)));

#define AS1 __attribute__((address_space(1)))
#define AS3 __attribute__((address_space(3)))

__device__ __forceinline__ void gload_lds16(const void* g, void* l) {
  __builtin_amdgcn_global_load_lds((const AS1 void*)g, (AS3 void*)l, 16, 0, 0);
}

#define MFMA16(a, b, c) __builtin_amdgcn_mfma_f32_16x16x32_bf16((a), (b), (c), 0, 0, 0)

// ---------------------------------------------------------------- fp32 -> bf16 (all 4 tensors, one dispatch)
__global__ __launch_bounds__(256)
void cvt_all(const float* __restrict__ sem, const float* __restrict__ wq,
             const float* __restrict__ wk, const float* __restrict__ wa,
             __bf16* __restrict__ semb, __bf16* __restrict__ wcat) {
  int i = blockIdx.x * 256 + threadIdx.x;
  if (i >= 2409472) return;
  const float* in;
  __bf16* out;
  int j;
  if (i < 1310720) { in = sem; out = semb; j = i; }
  else if (i < 1835008) { in = wq; out = wcat; j = i - 1310720; }
  else if (i < 2359296) { in = wk; out = wcat + 4194304; j = i - 1835008; }
  else { in = wa; out = wcat + 8388608; j = i - 2359296; }
  const float4* p = (const float4*)in;
  float4 a = p[2 * j], b = p[2 * j + 1];
  bf16x8 v;
  v[0] = (__bf16)a.x; v[1] = (__bf16)a.y; v[2] = (__bf16)a.z; v[3] = (__bf16)a.w;
  v[4] = (__bf16)b.x; v[5] = (__bf16)b.y; v[6] = (__bf16)b.z; v[7] = (__bf16)b.w;
  *(bf16x8*)(out + (size_t)j * 8) = v;
}

// ---------------------------------------------------------------- fused projection GEMM, 192x128 tiles (r6-proven)
// C[5184(pad),4352] = semb[5120,2048] @ Wcat[4292,2048]^T.
// cols [0,2048)->Qb bf16 +qb; [2048,4096)->Kb bf16 +kb; [4096,4292)->adj sigmoid.
// 512 thr = 8 waves (4M x 2N), wave tile 48x64. BK=64, 32 iters.
// LDS = 80 KiB exactly (A dbuf 2x24 KiB + B dbuf 2x16 KiB) -> 2 blocks/CU = 16 waves/CU:
// cross-block + wave-count TLP hides staging latency; one vmcnt(0)+barrier per iter.
// This exact config beat 5 structural variants (r7-r10: ring-3, BK=32, 4-wave, 8-phase port).
__global__ __launch_bounds__(512, 4)
void gemm_fused(const __bf16* __restrict__ A, const __bf16* __restrict__ B,
                const float* __restrict__ qbias, const float* __restrict__ kbias,
                const float* __restrict__ abias, __bf16* __restrict__ Qo,
                __bf16* __restrict__ Ko, float* __restrict__ adj) {
  __shared__ char smem[81920];
  char* smc = smem;
  // bijective XCD chunking (nwg=918, q=114, r=6) + 8-wide tn-band, tm-major in band
  const int bid = blockIdx.x;
  const int xcd = bid & 7, sidx = bid >> 3;
  const int wgid = (xcd < 6 ? xcd * 115 : 690 + (xcd - 6) * 114) + sidx;
  int tm, tn;
  if (wgid < 864) {
    const int band = wgid / 216, rem = wgid % 216;
    tm = rem >> 3;
    tn = band * 8 + (rem & 7);
  } else {
    const int rem = wgid - 864;
    tm = rem >> 1;
    tn = 32 + (rem & 1);
  }

  const int t = threadIdx.x;
  const int lane = t & 63;
  const int w = t >> 6, wm = w >> 1, wn = w & 1;

  // staging constants (linear LDS dest; swizzle folded into global source column)
  const int r0 = t >> 3;                       // 0..63
  const int colx = ((t & 7) ^ (r0 & 7)) * 8;   // pre-swizzled source column (elements)
  const int t16 = t * 16;

#define STAGE_A(kk, pb) do {                                                 \
    char* dstA = smc + (pb) * 24576 + t16;                                   \
    int gr0 = tm * 192 + r0;        gr0 = gr0 < 5120 ? gr0 : 5119;           \
    int gr1 = tm * 192 + 64 + r0;   gr1 = gr1 < 5120 ? gr1 : 5119;           \
    int gr2 = tm * 192 + 128 + r0;  gr2 = gr2 < 5120 ? gr2 : 5119;           \
    gload_lds16(A + (size_t)gr0 * 2048 + (kk) * 64 + colx, dstA);            \
    gload_lds16(A + (size_t)gr1 * 2048 + (kk) * 64 + colx, dstA + 8192);     \
    gload_lds16(A + (size_t)gr2 * 2048 + (kk) * 64 + colx, dstA + 16384);    \
  } while (0)

#define STAGE_B(kk, pb) do {                                                 \
    char* dstB = smc + 49152 + (pb) * 16384 + t16;                           \
    int gr0 = tn * 128 + r0;        gr0 = gr0 < 4292 ? gr0 : 4291;           \
    int gr1 = tn * 128 + 64 + r0;   gr1 = gr1 < 4292 ? gr1 : 4291;           \
    gload_lds16(B + (size_t)gr0 * 2048 + (kk) * 64 + colx, dstB);            \
    gload_lds16(B + (size_t)gr1 * 2048 + (kk) * 64 + colx, dstB + 8192);     \
  } while (0)

  // fragment-read constants (swizzled ds_read)
  const int rbase = (lane & 15) * 128;
  const int g16 = (lane >> 4) * 16;
  const int x16 = (lane & 7) << 4;
  const int aoff = wm * 6144 + rbase;   // wm*48 rows * 128B
  const int boff = wn * 8192 + rbase;   // wn*64 rows * 128B

#define LDA(ab, m, kh) (*(const bf16x8*)((ab) + aoff + (m) * 2048 + ((((kh) * 64) + g16) ^ x16)))
#define LDB(bb, n, kh) (*(const bf16x8*)((bb) + boff + (n) * 2048 + ((((kh) * 64) + g16) ^ x16)))

  f32x4 acc[3][4];
#pragma unroll
  for (int m = 0; m < 3; ++m)
#pragma unroll
    for (int n = 0; n < 4; ++n) acc[m][n] = (f32x4){0.f, 0.f, 0.f, 0.f};

  // prologue: tile 0
  STAGE_A(0, 0); STAGE_B(0, 0);
  asm volatile("s_waitcnt vmcnt(0)" ::: "memory");
  __builtin_amdgcn_s_barrier();

  for (int j = 0; j < 32; ++j) {
    char* Ab = smc + (j & 1) * 24576;
    char* Bb = smc + 49152 + (j & 1) * 16384;
    bf16x8 af[3][2], bf[2][2], bg[2][2];
    // frags for cluster 1
#pragma unroll
    for (int m = 0; m < 3; ++m) { af[m][0] = LDA(Ab, m, 0); af[m][1] = LDA(Ab, m, 1); }
#pragma unroll
    for (int n = 0; n < 2; ++n) { bf[n][0] = LDB(Bb, n, 0); bf[n][1] = LDB(Bb, n, 1); }
    // stage next tile into other buffer
    if (j < 31) { STAGE_A(j + 1, (j + 1) & 1); STAGE_B(j + 1, (j + 1) & 1); }
    __builtin_amdgcn_s_setprio(1);
#pragma unroll
    for (int m = 0; m < 3; ++m)
#pragma unroll
      for (int n = 0; n < 2; ++n) {
        acc[m][n] = MFMA16(af[m][0], bf[n][0], acc[m][n]);
        acc[m][n] = MFMA16(af[m][1], bf[n][1], acc[m][n]);
      }
    __builtin_amdgcn_s_setprio(0);
    // frags + cluster 2
#pragma unroll
    for (int n = 0; n < 2; ++n) { bg[n][0] = LDB(Bb, n + 2, 0); bg[n][1] = LDB(Bb, n + 2, 1); }
    __builtin_amdgcn_s_setprio(1);
#pragma unroll
    for (int m = 0; m < 3; ++m)
#pragma unroll
      for (int n = 0; n < 2; ++n) {
        acc[m][n + 2] = MFMA16(af[m][0], bg[n][0], acc[m][n + 2]);
        acc[m][n + 2] = MFMA16(af[m][1], bg[n][1], acc[m][n + 2]);
      }
    __builtin_amdgcn_s_setprio(0);
    if (j < 31) asm volatile("s_waitcnt vmcnt(0)" ::: "memory");
    __builtin_amdgcn_s_barrier();
  }

  // ---- epilogue
  if (tn < 32) {
    // bias-add + bf16 into LDS [192][136], then coalesced 16B row-major stores
    __bf16* so = (__bf16*)smc;
    const float* bias = (tn < 16) ? (qbias + tn * 128) : (kbias + (tn - 16) * 128);
#pragma unroll
    for (int n = 0; n < 4; ++n) {
      const int colb = wn * 64 + n * 16 + (lane & 15);
      const float bv = bias[colb];
#pragma unroll
      for (int m = 0; m < 3; ++m) {
        const int rw = wm * 48 + m * 16 + (lane >> 4) * 4;
#pragma unroll
        for (int jj = 0; jj < 4; ++jj)
          so[(rw + jj) * 136 + colb] = (__bf16)(acc[m][n][jj] + bv);
      }
    }
    __syncthreads();
    __bf16* dst = (tn < 16) ? (Qo + tn * 128) : (Ko + (tn - 16) * 128);
    for (int idx = t; idx < 3072; idx += 512) {  // 192 rows x 16 16B-chunks
      const int row = idx >> 4, c = idx & 15;
      const int grow = tm * 192 + row;
      if (grow < 5120) {
        bf16x8 v = *(const bf16x8*)(so + row * 136 + c * 8);
        *(bf16x8*)(dst + (size_t)grow * 2048 + c * 8) = v;
      }
    }
  } else {
    // adj region: scattered f32 sigmoid stores (small)
#pragma unroll
    for (int n = 0; n < 4; ++n) {
      const int colg = (tn - 32) * 128 + wn * 64 + n * 16 + (lane & 15);
      if (colg < 196) {
        const float bv = abias[colg];
#pragma unroll
        for (int m = 0; m < 3; ++m)
#pragma unroll
          for (int jj = 0; jj < 4; ++jj) {
            const int row = tm * 192 + wm * 48 + m * 16 + (lane >> 4) * 4 + jj;
            if (row < 5120) {
              const float v = acc[m][n][jj] + bv;
              adj[(size_t)row * 196 + colg] = 1.f / (1.f + __expf(-v));
            }
          }
      }
    }
  }
#undef STAGE_A
#undef STAGE_B
#undef LDA
#undef LDB
}

// ---------------------------------------------------------------- attention 1/3: partial S
// grid (64 b x 8 kq): S_part[b][kq] = Q_b[:, kq*256..+256] @ K_b[...]^T  (f32 80x80)
__global__ __launch_bounds__(256)
void attn_s(const __bf16* __restrict__ Qb, const __bf16* __restrict__ Kb,
            float* __restrict__ Spart) {
  __shared__ char smem[81920];
  __bf16* sQ = (__bf16*)smem;            // [80][256]
  __bf16* sK = (__bf16*)(smem + 40960);  // [80][256]
  const int b = blockIdx.x >> 3, kq = blockIdx.x & 7;
  const int kc = kq * 256;
  const int t = threadIdx.x, lane = t & 63, w = t >> 6;
  const __bf16* Qbase = Qb + (size_t)b * 163840;
  const __bf16* Kbase = Kb + (size_t)b * 163840;

#pragma unroll
  for (int s = 0; s < 10; ++s) {
    const int i = t + s * 256;
    const int row = i >> 5, cb = i & 31;
    gload_lds16(Qbase + (size_t)row * 2048 + kc + cb * 8, sQ + i * 8);
  }
#pragma unroll
  for (int s = 0; s < 10; ++s) {
    const int i = t + s * 256;
    const int row = i >> 5, cb = i & 31;
    gload_lds16(Kbase + (size_t)row * 2048 + kc + cb * 8, sK + i * 8);
  }
  __syncthreads();

  f32x4 acc[7];
#pragma unroll
  for (int u = 0; u < 7; ++u) acc[u] = (f32x4){0.f, 0.f, 0.f, 0.f};
#pragma unroll
  for (int u = 0; u < 7; ++u) {
    const int tl = w + u * 4;
    if (tl < 25) {
      const int qi = tl / 5, kj = tl % 5;
#pragma unroll
      for (int k0 = 0; k0 < 256; k0 += 32) {
        bf16x8 a = *(const bf16x8*)(sQ + (qi * 16 + (lane & 15)) * 256 + k0 + (lane >> 4) * 8);
        bf16x8 kk = *(const bf16x8*)(sK + (kj * 16 + (lane & 15)) * 256 + k0 + (lane >> 4) * 8);
        acc[u] = MFMA16(a, kk, acc[u]);
      }
    }
  }
  float* Sp = Spart + (size_t)(b * 8 + kq) * 6400;
#pragma unroll
  for (int u = 0; u < 7; ++u) {
    const int tl = w + u * 4;
    if (tl < 25) {
      const int qi = tl / 5, kj = tl % 5;
#pragma unroll
      for (int jj = 0; jj < 4; ++jj) {
        const int r = qi * 16 + (lane >> 4) * 4 + jj;
        const int c = kj * 16 + (lane & 15);
        Sp[r * 80 + c] = acc[u][jj];
      }
    }
  }
}

// ---------------------------------------------------------------- attention 2/3: softmax
// grid 64: sum 8 partials, softmax(S*scale*mask), write P bf16 [80][96] (zero-padded)
__global__ __launch_bounds__(256)
void attn_soft(const float* __restrict__ Spart, const float* __restrict__ mask,
               __bf16* __restrict__ Pg) {
  __shared__ float S[80 * 81];
  const int b = blockIdx.x, t = threadIdx.x;
  const float* Sp = Spart + (size_t)b * 8 * 6400;
  for (int idx = t; idx < 6400; idx += 256) {
    float s = 0.f;
#pragma unroll
    for (int p = 0; p < 8; ++p) s += Sp[p * 6400 + idx];
    const int r = idx / 80, c = idx - r * 80;
    S[r * 81 + c] = s;
  }
  __syncthreads();
  if (t < 80) {
    const float scale = 0.02209708691207961f;  // 1/sqrt(2048)
    float mx = -1e30f;
    for (int k = 0; k < 80; ++k) {
      float v = S[t * 81 + k] * scale * mask[t * 80 + k];
      S[t * 81 + k] = v;
      mx = fmaxf(mx, v);
    }
    float sum = 0.f;
    for (int k = 0; k < 80; ++k) {
      float e = __expf(S[t * 81 + k] - mx);
      S[t * 81 + k] = e;
      sum += e;
    }
    const float r = 1.f / sum;
    __bf16* Pr = Pg + (size_t)b * 7680 + t * 96;
    for (int k = 0; k < 80; ++k) Pr[k] = (__bf16)(S[t * 81 + k] * r);
    for (int k = 80; k < 96; ++k) Pr[k] = (__bf16)0.f;
  }
}

// ---------------------------------------------------------------- attention 3/3: PV + epilogue
__global__ __launch_bounds__(256)
void attn_pv(const __bf16* __restrict__ Pg, const float* __restrict__ feats,
             const float* __restrict__ adj, float* __restrict__ out) {
  __shared__ __bf16 Ft[64 * 104];
  const int b = blockIdx.x >> 2, hq = blockIdx.x & 3;
  const int hb = hq * 49;
  const int t = threadIdx.x, lane = t & 63, w = t >> 6;
  for (int idx = t; idx < 4704; idx += 256) {  // 96*49
    const int k = idx / 49, h = idx - k * 49;
    Ft[h * 104 + k] = (k < 80) ? (__bf16)feats[(size_t)b * 15680 + k * 196 + hb + h]
                               : (__bf16)0.f;
  }
  __syncthreads();
  const __bf16* Pb = Pg + (size_t)b * 7680;
#pragma unroll
  for (int u = 0; u < 5; ++u) {
    const int tl = w + u * 4;  // 0..19
    const int ci = tl >> 2, hj = tl & 3;
    f32x4 a2 = (f32x4){0.f, 0.f, 0.f, 0.f};
#pragma unroll
    for (int k0 = 0; k0 < 96; k0 += 32) {
      bf16x8 pa = *(const bf16x8*)(Pb + (ci * 16 + (lane & 15)) * 96 + k0 + (lane >> 4) * 8);
      bf16x8 fb = *(const bf16x8*)(Ft + (hj * 16 + (lane & 15)) * 104 + k0 + (lane >> 4) * 8);
      a2 = MFMA16(pa, fb, a2);
    }
#pragma unroll
    for (int jj = 0; jj < 4; ++jj) {
      const int c = ci * 16 + (lane >> 4) * 4 + jj;
      const int h2 = hj * 16 + (lane & 15);
      if (h2 < 49) {
        const size_t o = (size_t)b * 15680 + (size_t)c * 196 + hb + h2;
        out[o] = (feats[o] + a2[jj]) * adj[o];
      }
    }
  }
}

// ---------------------------------------------------------------- launch
extern "C" void kernel_launch(void* const* d_in, const int* in_sizes, int n_in,
                              void* d_out, int out_size, void* d_ws, size_t ws_size,
                              hipStream_t stream) {
  const float* features = (const float*)d_in[0];
  const float* sem      = (const float*)d_in[1];
  const float* mask     = (const float*)d_in[2];
  const float* Wq_w     = (const float*)d_in[3];
  const float* Wq_b     = (const float*)d_in[4];
  const float* Wk_w     = (const float*)d_in[5];
  const float* Wk_b     = (const float*)d_in[6];
  const float* Wa_w     = (const float*)d_in[7];
  const float* Wa_b     = (const float*)d_in[8];
  float* out = (float*)d_out;

  char* ws = (char*)d_ws;
  __bf16* semb = (__bf16*)ws;                   // 5120x2048 bf16
  __bf16* wcat = (__bf16*)(ws + 20971520);      // 4292x2048 bf16
  __bf16* Qb   = (__bf16*)(ws + 38551552);
  __bf16* Kb   = (__bf16*)(ws + 59523072);
  float*  adj  = (float*)(ws + 80494592);       // 5120x196 f32 (total 84.5 MB)
  float*  Spart = (float*)ws;                   // 64*8*6400 f32 = 13.1 MB (aliases semb)
  __bf16* Pg    = (__bf16*)(ws + 20971520);     // aliases wcat (dead after gemm)

  cvt_all<<<9412, 256, 0, stream>>>(sem, Wq_w, Wk_w, Wa_w, semb, wcat);
  gemm_fused<<<918, 512, 0, stream>>>(semb, wcat, Wq_b, Wk_b, Wa_b, Qb, Kb, adj);
  attn_s<<<512, 256, 0, stream>>>(Qb, Kb, Spart);
  attn_soft<<<64, 256, 0, stream>>>(Spart, mask, Pg);
  attn_pv<<<256, 256, 0, stream>>>(Pg, features, adj, out);
}